// Round 1
// baseline (646.638 us; speedup 1.0000x reference)
//
#include <hip/hip_runtime.h>
#include <math.h>

typedef unsigned long long u64;
typedef unsigned int u32;

#define H0 384
#define W0 512
#define H1 192
#define W1 256
#define HW0 (H0*W0)   /* 196608 */
#define HW1 (H1*W1)   /* 49152  */
#define NSEL 512
#define NMATCH 128
#define CAP 32768
#define BND_CAP 2048
#define NROW 4

// ---------------------------------------------------------------------------
// Zero the per-extraction candidate counters (ws is poisoned 0xAA each call).
__global__ void zero_cnt_kernel(u32* cnt) {
    if (threadIdx.x < 4) cnt[threadIdx.x] = 0u;
}

// ---------------------------------------------------------------------------
// 3x3 NMS + score threshold; compact candidates as sortable u64 keys:
//   key = (float_bits(score) << 32) | (0xFFFFFFFF - pixel_index)
// Descending key order == score desc, index asc (jax.lax.top_k tie rule).
__global__ void nms_score_kernel(const float* __restrict__ rep,
                                 const float* __restrict__ rel,
                                 int H, int W, int pix_base,
                                 u64* __restrict__ cand, u32* __restrict__ cnt) {
    int p = blockIdx.x * blockDim.x + threadIdx.x;
    int HW = H * W;
    if (p >= HW) return;
    int r = p / W, c = p - r * W;
    float v = rep[p];
    bool ismax = true;
    for (int dr = -1; dr <= 1; ++dr) {
        int rr = r + dr;
        if (rr < 0 || rr >= H) continue;
        for (int dc = -1; dc <= 1; ++dc) {
            if (dr == 0 && dc == 0) continue;
            int cc = c + dc;
            if (cc < 0 || cc >= W) continue;
            ismax = ismax && (v >= rep[rr * W + cc]);
        }
    }
    if (!ismax) return;
    float m = sqrtf(v * rel[p]);
    if (!(m >= 0.7f)) return;
    u32 pos = atomicAdd(cnt, 1u);
    if (pos < CAP) {
        u64 key = ((u64)__float_as_uint(m) << 32) |
                  (u64)(0xFFFFFFFFu - (u32)(pix_base + p));
        cand[pos] = key;
    }
}

// ---------------------------------------------------------------------------
// Exact top-512 per extraction. Scores all lie in [0.7, 1) -> same exponent,
// so the byte (bits>>16)&0xFF is monotone in score. Histogram -> threshold
// byte b*; everything strictly above b* is in; boundary bin sorted by full
// key (bitonic, desc) to pick the remainder.
__global__ void __launch_bounds__(1024)
select512_kernel(const u64* __restrict__ cand_all, const u32* __restrict__ cnt_all,
                 u32* __restrict__ sel_pix, float* __restrict__ sel_score) {
    int e = blockIdx.x;
    int tid = threadIdx.x;
    const u64* cand = cand_all + (size_t)e * CAP;
    __shared__ u32 hist[256];
    __shared__ int s_b;
    __shared__ u32 n_top, n_bnd;
    __shared__ u64 topl[NSEL];
    __shared__ u64 bnd[BND_CAP];

    u32 n = min(cnt_all[e], (u32)CAP);
    for (int i = tid; i < 256; i += 1024) hist[i] = 0;
    if (tid == 0) { n_top = 0; n_bnd = 0; }
    __syncthreads();
    for (u32 i = tid; i < n; i += 1024)
        atomicAdd(&hist[(u32)(cand[i] >> 48) & 0xFFu], 1u);
    __syncthreads();
    if (tid == 0) {
        u32 acc = 0;
        int b = 255;
        for (; b >= 0; --b) {
            if (acc + hist[b] >= NSEL) break;
            acc += hist[b];
        }
        if (b < 0) b = 0;
        s_b = b;
    }
    __syncthreads();
    int bstar = s_b;
    for (u32 i = tid; i < n; i += 1024) {
        u64 k = cand[i];
        int byt = (int)((u32)(k >> 48) & 0xFFu);
        if (byt > bstar) {
            u32 p = atomicAdd(&n_top, 1u);
            if (p < NSEL) topl[p] = k;
        } else if (byt == bstar) {
            u32 p = atomicAdd(&n_bnd, 1u);
            if (p < BND_CAP) bnd[p] = k;
        }
    }
    __syncthreads();
    u32 m = min(n_bnd, (u32)BND_CAP);
    u32 P = 2;
    while (P < m) P <<= 1;
    for (u32 i = tid; i < P; i += 1024)
        if (i >= m) bnd[i] = 0ull;
    __syncthreads();
    // bitonic sort, descending
    for (u32 k = 2; k <= P; k <<= 1) {
        for (u32 j = k >> 1; j > 0; j >>= 1) {
            for (u32 i = tid; i < P; i += 1024) {
                u32 ixj = i ^ j;
                if (ixj > i) {
                    u64 a = bnd[i], b2 = bnd[ixj];
                    bool up = ((i & k) == 0);
                    if (up ? (a < b2) : (a > b2)) { bnd[i] = b2; bnd[ixj] = a; }
                }
            }
            __syncthreads();
        }
    }
    u32 k1 = min(n_top, (u32)NSEL);
    if (tid < NSEL) {
        u64 k;
        if ((u32)tid < k1) k = topl[tid];
        else {
            u32 r = (u32)tid - k1;
            k = (r < m) ? bnd[r] : 0ull;
        }
        u32 pix;
        float sc;
        if (k == 0ull) { pix = 0u; sc = -1.0f; }  // unreachable with this data
        else {
            pix = 0xFFFFFFFFu - (u32)(k & 0xFFFFFFFFu);
            sc = __uint_as_float((u32)(k >> 32));
        }
        sel_pix[e * NSEL + tid] = pix;
        sel_score[e * NSEL + tid] = sc;
    }
}

// ---------------------------------------------------------------------------
// Gather descriptor (scaled by score), apply Wq (img1) / Wk (img2), emit
// pixel locations. q stored [b][n][r] (r contiguous), kT stored [b][r][m]
// (m contiguous) for coalesced match-kernel reads.
__global__ void gather_tf_kernel(const float* __restrict__ d1s0, const float* __restrict__ d1s1,
                                 const float* __restrict__ d2s0, const float* __restrict__ d2s1,
                                 const float* __restrict__ Wq, const float* __restrict__ Wk,
                                 const u32* __restrict__ sel_pix, const float* __restrict__ sel_score,
                                 float* __restrict__ q, float* __restrict__ kT,
                                 float* __restrict__ loc1, float* __restrict__ loc2) {
    int e = blockIdx.y;
    int b = e & 1, img = e >> 1;
    int n = blockIdx.x;
    int tid = threadIdx.x;  // channel / output channel
    u32 pix = sel_pix[e * NSEL + n];
    float sc = sel_score[e * NSEL + n];
    __shared__ float v[128];
    const float* ds;
    int loff;
    float lr, lc;
    if (pix < (u32)HW0) {
        ds = img ? d2s0 : d1s0;
        loff = (b * 128 + tid) * HW0 + (int)pix;
        lr = (float)((int)pix >> 9);          // /512
        lc = (float)((int)pix & 511);
    } else {
        int p1 = (int)pix - HW0;
        ds = img ? d2s1 : d1s1;
        loff = (b * 128 + tid) * HW1 + p1;
        lr = 2.0f * (float)(p1 >> 8);         // /256, scale 2
        lc = 2.0f * (float)(p1 & 255);
    }
    v[tid] = ds[loff] * sc;
    __syncthreads();
    const float* W = img ? Wk : Wq;
    float acc = 0.f;
#pragma unroll 8
    for (int c2 = 0; c2 < 128; ++c2) acc += W[tid * 128 + c2] * v[c2];
    if (img == 0) {
        q[(b * NSEL + n) * 128 + tid] = acc;
        if (tid == 0) {
            loc1[(b * 2 + 0) * NSEL + n] = lr;
            loc1[(b * 2 + 1) * NSEL + n] = lc;
        }
    } else {
        kT[(b * 128 + tid) * NSEL + n] = acc;
        if (tid == 0) {
            loc2[(b * 2 + 0) * NSEL + n] = lr;
            loc2[(b * 2 + 1) * NSEL + n] = lc;
        }
    }
}

// ---------------------------------------------------------------------------
// Fused match: rel row, top-2, softmax(rel*512) location expectation, ratio.
// One block handles NROW=4 query rows; thread m covers key m.
__global__ void __launch_bounds__(512)
match_kernel(const float* __restrict__ q, const float* __restrict__ kT,
             const float* __restrict__ loc2, const float* __restrict__ Wv,
             float* __restrict__ ratios, float* __restrict__ corr) {
    int blk = blockIdx.x;
    int b = blk / (NSEL / NROW);
    int nt = blk % (NSEL / NROW);
    int tid = threadIdx.x;  // m
    __shared__ float qs[NROW][128];
    {
        int r = tid >> 7, c2 = tid & 127;
        qs[r][c2] = q[((b * NSEL) + nt * NROW + r) * 128 + c2];
    }
    __syncthreads();
    const float* kt = kT + (size_t)b * 128 * NSEL;
    float rel0 = 0.f, rel1 = 0.f, rel2 = 0.f, rel3 = 0.f;
#pragma unroll 4
    for (int c2 = 0; c2 < 128; ++c2) {
        float kv = kt[c2 * NSEL + tid];
        rel0 += qs[0][c2] * kv;
        rel1 += qs[1][c2] * kv;
        rel2 += qs[2][c2] * kv;
        rel3 += qs[3][c2] * kv;
    }
    float l2x = loc2[(b * 2 + 0) * NSEL + tid];
    float l2y = loc2[(b * 2 + 1) * NSEL + tid];
    float v0 = Wv[0] * l2x + Wv[1] * l2y;
    float v1 = Wv[2] * l2x + Wv[3] * l2y;

    __shared__ float red[8][8];
    float relr[NROW] = {rel0, rel1, rel2, rel3};
    int wave = tid >> 6, lane = tid & 63;
    for (int r = 0; r < NROW; ++r) {
        float relv = relr[r];
        // top-2 butterfly reduce (xor shuffles stay in-range)
        float b1 = relv, b2v = -INFINITY;
        for (int off = 32; off > 0; off >>= 1) {
            float o1 = __shfl_xor(b1, off);
            float o2 = __shfl_xor(b2v, off);
            float m1 = fmaxf(b1, o1);
            float m2 = fmaxf(fminf(b1, o1), fmaxf(b2v, o2));
            b1 = m1; b2v = m2;
        }
        if (lane == 0) { red[wave][0] = b1; red[wave][1] = b2v; }
        __syncthreads();
        if (tid == 0) {
            float t1 = red[0][0], t2 = red[0][1];
            for (int w2 = 1; w2 < 8; ++w2) {
                float o1 = red[w2][0], o2 = red[w2][1];
                float m1 = fmaxf(t1, o1);
                float m2 = fmaxf(fminf(t1, o1), fmaxf(t2, o2));
                t1 = m1; t2 = m2;
            }
            red[0][2] = t1; red[0][3] = t2;
        }
        __syncthreads();
        float top1 = red[0][2], top2 = red[0][3];
        float ex = expf(512.0f * (relv - top1));
        float sw = ex, swx = ex * v0, swy = ex * v1;
        for (int off = 32; off > 0; off >>= 1) {
            sw  += __shfl_xor(sw, off);
            swx += __shfl_xor(swx, off);
            swy += __shfl_xor(swy, off);
        }
        if (lane == 0) { red[wave][4] = sw; red[wave][5] = swx; red[wave][6] = swy; }
        __syncthreads();
        if (tid == 0) {
            float s = 0.f, sx = 0.f, sy = 0.f;
            for (int w2 = 0; w2 < 8; ++w2) { s += red[w2][4]; sx += red[w2][5]; sy += red[w2][6]; }
            int n = nt * NROW + r;
            float a1 = acosf(fminf(fmaxf(top1, -1.f), 1.f));
            float a2 = acosf(fminf(fmaxf(top2, -1.f), 1.f));
            ratios[b * NSEL + n] = a1 / a2;
            corr[(b * 2 + 0) * NSEL + n] = sx / s;
            corr[(b * 2 + 1) * NSEL + n] = sy / s;
        }
        __syncthreads();
    }
}

// ---------------------------------------------------------------------------
// Sort 512 ratios ascending (tie -> lower index, matching lax.top_k on
// -ratios), emit the first 128 matches.
__global__ void finalize_kernel(const float* __restrict__ ratios,
                                const float* __restrict__ loc1, const float* __restrict__ corr,
                                float* __restrict__ out) {
    int b = blockIdx.x;
    int tid = threadIdx.x;  // 256
    __shared__ u64 keys[NSEL];
    for (int i = tid; i < NSEL; i += 256)
        keys[i] = ((u64)__float_as_uint(ratios[b * NSEL + i]) << 32) | (u32)i;
    __syncthreads();
    for (u32 k = 2; k <= NSEL; k <<= 1) {
        for (u32 j = k >> 1; j > 0; j >>= 1) {
            for (u32 i = tid; i < NSEL; i += 256) {
                u32 ixj = i ^ j;
                if (ixj > i) {
                    u64 a = keys[i], c2 = keys[ixj];
                    bool up = ((i & k) == 0);
                    if (up ? (a > c2) : (a < c2)) { keys[i] = c2; keys[ixj] = a; }
                }
            }
            __syncthreads();
        }
    }
    if (tid < NMATCH) {
        u32 n = (u32)(keys[tid] & 0xFFFFFFFFu);
        out[(b * 4 + 0) * NMATCH + tid] = loc1[(b * 2 + 0) * NSEL + n];
        out[(b * 4 + 1) * NMATCH + tid] = loc1[(b * 2 + 1) * NSEL + n];
        out[(b * 4 + 2) * NMATCH + tid] = corr[(b * 2 + 0) * NSEL + n];
        out[(b * 4 + 3) * NMATCH + tid] = corr[(b * 2 + 1) * NSEL + n];
    }
}

// ---------------------------------------------------------------------------
extern "C" void kernel_launch(void* const* d_in, const int* in_sizes, int n_in,
                              void* d_out, int out_size, void* d_ws, size_t ws_size,
                              hipStream_t stream) {
    const float* rep1_s0 = (const float*)d_in[0];
    const float* rel1_s0 = (const float*)d_in[1];
    const float* desc1_s0 = (const float*)d_in[2];
    const float* rep1_s1 = (const float*)d_in[3];
    const float* rel1_s1 = (const float*)d_in[4];
    const float* desc1_s1 = (const float*)d_in[5];
    const float* rep2_s0 = (const float*)d_in[6];
    const float* rel2_s0 = (const float*)d_in[7];
    const float* desc2_s0 = (const float*)d_in[8];
    const float* rep2_s1 = (const float*)d_in[9];
    const float* rel2_s1 = (const float*)d_in[10];
    const float* desc2_s1 = (const float*)d_in[11];
    const float* Wq = (const float*)d_in[12];
    const float* Wk = (const float*)d_in[13];
    const float* Wv = (const float*)d_in[14];
    float* out = (float*)d_out;

    char* w = (char*)d_ws;
    auto alloc = [&](size_t bytes) {
        char* p = w;
        w += (bytes + 255) & ~(size_t)255;
        return p;
    };
    u32* cnt       = (u32*)alloc(4 * sizeof(u32));
    u64* cand      = (u64*)alloc((size_t)4 * CAP * sizeof(u64));
    u32* sel_pix   = (u32*)alloc(4 * NSEL * sizeof(u32));
    float* sel_score = (float*)alloc(4 * NSEL * sizeof(float));
    float* q       = (float*)alloc((size_t)2 * NSEL * 128 * sizeof(float));
    float* kT      = (float*)alloc((size_t)2 * 128 * NSEL * sizeof(float));
    float* loc1    = (float*)alloc(2 * 2 * NSEL * sizeof(float));
    float* loc2    = (float*)alloc(2 * 2 * NSEL * sizeof(float));
    float* ratios  = (float*)alloc(2 * NSEL * sizeof(float));
    float* corr    = (float*)alloc(2 * 2 * NSEL * sizeof(float));

    zero_cnt_kernel<<<1, 64, 0, stream>>>(cnt);
    for (int e = 0; e < 4; ++e) {
        int b = e & 1, img = e >> 1;
        const float* rs0 = img ? rep2_s0 : rep1_s0;
        const float* ls0 = img ? rel2_s0 : rel1_s0;
        const float* rs1 = img ? rep2_s1 : rep1_s1;
        const float* ls1 = img ? rel2_s1 : rel1_s1;
        nms_score_kernel<<<(HW0 + 255) / 256, 256, 0, stream>>>(
            rs0 + (size_t)b * HW0, ls0 + (size_t)b * HW0, H0, W0, 0,
            cand + (size_t)e * CAP, cnt + e);
        nms_score_kernel<<<(HW1 + 255) / 256, 256, 0, stream>>>(
            rs1 + (size_t)b * HW1, ls1 + (size_t)b * HW1, H1, W1, HW0,
            cand + (size_t)e * CAP, cnt + e);
    }
    select512_kernel<<<4, 1024, 0, stream>>>(cand, cnt, sel_pix, sel_score);
    gather_tf_kernel<<<dim3(NSEL, 4), 128, 0, stream>>>(
        desc1_s0, desc1_s1, desc2_s0, desc2_s1, Wq, Wk,
        sel_pix, sel_score, q, kT, loc1, loc2);
    match_kernel<<<2 * (NSEL / NROW), 512, 0, stream>>>(q, kT, loc2, Wv, ratios, corr);
    finalize_kernel<<<2, 256, 0, stream>>>(ratios, loc1, corr, out);
}

// Round 2
// 613.464 us; speedup vs baseline: 1.0541x; 1.0541x over previous
//
#include <hip/hip_runtime.h>
#include <math.h>

typedef unsigned long long u64;
typedef unsigned int u32;

#define H0 384
#define W0 512
#define H1 192
#define W1 256
#define HW0 (H0*W0)   /* 196608 */
#define HW1 (H1*W1)   /* 49152  */
#define NSEL 512
#define NMATCH 128
#define CAP 32768
#define BND_CAP 2048
#define NROW 4
#define KPB 16        /* keypoints per gather block */

// ---------------------------------------------------------------------------
__global__ void zero_cnt_kernel(u32* cnt) {
    if (threadIdx.x < 4) cnt[threadIdx.x] = 0u;
}

// ---------------------------------------------------------------------------
// All 4 extractions x 2 scales in ONE launch. 3x3 NMS + score threshold;
// compact candidates as sortable u64 keys:
//   key = (float_bits(score) << 32) | (0xFFFFFFFF - pixel_index)
// Descending key order == score desc, index asc (jax.lax.top_k tie rule).
// Grid layout: per extraction e: 768 blocks (s0) + 192 blocks (s1) = 960.
__global__ void __launch_bounds__(256)
nms_all_kernel(const float* __restrict__ rep10, const float* __restrict__ rep11,
               const float* __restrict__ rep20, const float* __restrict__ rep21,
               const float* __restrict__ rel10, const float* __restrict__ rel11,
               const float* __restrict__ rel20, const float* __restrict__ rel21,
               u64* __restrict__ cand, u32* __restrict__ cnt) {
    int blk = blockIdx.x;
    int e = blk / 960;
    int r0 = blk - e * 960;
    int b = e & 1, img = e >> 1;
    int scale = (r0 < 768) ? 0 : 1;
    int pblk = scale ? (r0 - 768) : r0;
    int p = pblk * 256 + threadIdx.x;
    int H = scale ? H1 : H0, W = scale ? W1 : W0;
    int HW = H * W;
    const float* rep = scale ? (img ? rep21 : rep11) : (img ? rep20 : rep10);
    const float* rel = scale ? (img ? rel21 : rel11) : (img ? rel20 : rel10);
    rep += (size_t)b * HW;
    rel += (size_t)b * HW;
    int r = p / W, c = p - r * W;
    float v = rep[p];
    bool ismax = true;
    for (int dr = -1; dr <= 1; ++dr) {
        int rr = r + dr;
        if (rr < 0 || rr >= H) continue;
        for (int dc = -1; dc <= 1; ++dc) {
            if (dr == 0 && dc == 0) continue;
            int cc = c + dc;
            if (cc < 0 || cc >= W) continue;
            ismax = ismax && (v >= rep[rr * W + cc]);
        }
    }
    if (!ismax) return;
    float m = sqrtf(v * rel[p]);
    if (!(m >= 0.7f)) return;
    u32 pos = atomicAdd(cnt + e, 1u);
    if (pos < CAP) {
        int pix_base = scale ? HW0 : 0;
        u64 key = ((u64)__float_as_uint(m) << 32) |
                  (u64)(0xFFFFFFFFu - (u32)(pix_base + p));
        cand[(size_t)e * CAP + pos] = key;
    }
}

// ---------------------------------------------------------------------------
// Exact top-512 per extraction (unchanged from R1 — absmax was 0.0).
__global__ void __launch_bounds__(1024)
select512_kernel(const u64* __restrict__ cand_all, const u32* __restrict__ cnt_all,
                 u32* __restrict__ sel_pix, float* __restrict__ sel_score) {
    int e = blockIdx.x;
    int tid = threadIdx.x;
    const u64* cand = cand_all + (size_t)e * CAP;
    __shared__ u32 hist[256];
    __shared__ int s_b;
    __shared__ u32 n_top, n_bnd;
    __shared__ u64 topl[NSEL];
    __shared__ u64 bnd[BND_CAP];

    u32 n = min(cnt_all[e], (u32)CAP);
    for (int i = tid; i < 256; i += 1024) hist[i] = 0;
    if (tid == 0) { n_top = 0; n_bnd = 0; }
    __syncthreads();
    for (u32 i = tid; i < n; i += 1024)
        atomicAdd(&hist[(u32)(cand[i] >> 48) & 0xFFu], 1u);
    __syncthreads();
    if (tid == 0) {
        u32 acc = 0;
        int b = 255;
        for (; b >= 0; --b) {
            if (acc + hist[b] >= NSEL) break;
            acc += hist[b];
        }
        if (b < 0) b = 0;
        s_b = b;
    }
    __syncthreads();
    int bstar = s_b;
    for (u32 i = tid; i < n; i += 1024) {
        u64 k = cand[i];
        int byt = (int)((u32)(k >> 48) & 0xFFu);
        if (byt > bstar) {
            u32 p = atomicAdd(&n_top, 1u);
            if (p < NSEL) topl[p] = k;
        } else if (byt == bstar) {
            u32 p = atomicAdd(&n_bnd, 1u);
            if (p < BND_CAP) bnd[p] = k;
        }
    }
    __syncthreads();
    u32 m = min(n_bnd, (u32)BND_CAP);
    u32 P = 2;
    while (P < m) P <<= 1;
    for (u32 i = tid; i < P; i += 1024)
        if (i >= m) bnd[i] = 0ull;
    __syncthreads();
    for (u32 k = 2; k <= P; k <<= 1) {
        for (u32 j = k >> 1; j > 0; j >>= 1) {
            for (u32 i = tid; i < P; i += 1024) {
                u32 ixj = i ^ j;
                if (ixj > i) {
                    u64 a = bnd[i], b2 = bnd[ixj];
                    bool up = ((i & k) == 0);
                    if (up ? (a < b2) : (a > b2)) { bnd[i] = b2; bnd[ixj] = a; }
                }
            }
            __syncthreads();
        }
    }
    u32 k1 = min(n_top, (u32)NSEL);
    if (tid < NSEL) {
        u64 k;
        if ((u32)tid < k1) k = topl[tid];
        else {
            u32 r = (u32)tid - k1;
            k = (r < m) ? bnd[r] : 0ull;
        }
        u32 pix;
        float sc;
        if (k == 0ull) { pix = 0u; sc = -1.0f; }
        else {
            pix = 0xFFFFFFFFu - (u32)(k & 0xFFFFFFFFu);
            sc = __uint_as_float((u32)(k >> 32));
        }
        sel_pix[e * NSEL + tid] = pix;
        sel_score[e * NSEL + tid] = sc;
    }
}

// ---------------------------------------------------------------------------
// Gather + transform, LDS-staged. One block = 16 keypoints of one extraction.
// W staged transposed in LDS (pad 129 -> conflict-free both ways); gathered
// descriptors staged [c2][kp] (pad 36 -> aligned float4 over kp, 8-way write
// conflict only on the tiny gather phase). Matvec: thread=out channel,
// float4 over 4 keypoints: 1 b32 + 1 broadcast b128 per 4 FMA.
__global__ void __launch_bounds__(256)
gather_tf_kernel(const float* __restrict__ d1s0, const float* __restrict__ d1s1,
                 const float* __restrict__ d2s0, const float* __restrict__ d2s1,
                 const float* __restrict__ Wq, const float* __restrict__ Wk,
                 const u32* __restrict__ sel_pix, const float* __restrict__ sel_score,
                 float* __restrict__ q, float* __restrict__ kT,
                 float* __restrict__ loc1, float* __restrict__ loc2) {
    int e = blockIdx.y;
    int b = e & 1, img = e >> 1;
    int kp0 = blockIdx.x * KPB;
    int tid = threadIdx.x;
    __shared__ float Wt[128 * 129];   // Wt[c2*129+ch] = W[ch][c2]
    __shared__ float vb[128 * 36];    // vb[c2*36+kp]
    __shared__ u32 s_pix[KPB];
    __shared__ float s_sc[KPB];
    const float* W = img ? Wk : Wq;
    for (int i = tid; i < 16384; i += 256) {
        int row = i >> 7, col = i & 127;
        Wt[col * 129 + row] = W[i];
    }
    if (tid < KPB) {
        s_pix[tid] = sel_pix[e * NSEL + kp0 + tid];
        s_sc[tid] = sel_score[e * NSEL + kp0 + tid];
    }
    __syncthreads();
    for (int i = tid; i < KPB * 128; i += 256) {
        int kp = i >> 7, c2 = i & 127;
        u32 pix = s_pix[kp];
        float val;
        if (pix < (u32)HW0) {
            const float* ds = img ? d2s0 : d1s0;
            val = ds[((size_t)(b * 128 + c2)) * HW0 + pix];
        } else {
            const float* ds = img ? d2s1 : d1s1;
            val = ds[((size_t)(b * 128 + c2)) * HW1 + (pix - HW0)];
        }
        vb[c2 * 36 + kp] = val * s_sc[kp];
    }
    __syncthreads();
    int ch = tid & 127;
    int half = tid >> 7;               // each half: 2 groups of 4 kp
    for (int g = half * 2; g < half * 2 + 2; ++g) {
        float ax = 0.f, ay = 0.f, az = 0.f, aw = 0.f;
#pragma unroll 4
        for (int c2 = 0; c2 < 128; ++c2) {
            float w = Wt[c2 * 129 + ch];
            const float4 v4 = *(const float4*)&vb[c2 * 36 + g * 4];
            ax += w * v4.x; ay += w * v4.y; az += w * v4.z; aw += w * v4.w;
        }
        int n0 = kp0 + g * 4;
        if (img == 0) {
            q[((size_t)(b * NSEL) + n0 + 0) * 128 + ch] = ax;
            q[((size_t)(b * NSEL) + n0 + 1) * 128 + ch] = ay;
            q[((size_t)(b * NSEL) + n0 + 2) * 128 + ch] = az;
            q[((size_t)(b * NSEL) + n0 + 3) * 128 + ch] = aw;
        } else {
            float4* kr = (float4*)(kT + ((size_t)(b * 128) + ch) * NSEL + n0);
            *kr = make_float4(ax, ay, az, aw);
        }
    }
    if (tid < KPB) {
        u32 pix = s_pix[tid];
        float lr, lc;
        if (pix < (u32)HW0) { lr = (float)(pix >> 9); lc = (float)(pix & 511u); }
        else { u32 p1 = pix - HW0; lr = 2.f * (float)(p1 >> 8); lc = 2.f * (float)(p1 & 255u); }
        float* L = (img == 0) ? loc1 : loc2;
        L[(b * 2 + 0) * NSEL + kp0 + tid] = lr;
        L[(b * 2 + 1) * NSEL + kp0 + tid] = lc;
    }
}

// ---------------------------------------------------------------------------
// Fused match: rel rows, top-2, softmax(rel*512) expectation, acos ratio.
// NROW=4 query rows per block; thread m covers key m. Only 2 barriers.
__global__ void __launch_bounds__(512)
match_kernel(const float* __restrict__ q, const float* __restrict__ kT,
             const float* __restrict__ loc2, const float* __restrict__ Wv,
             float* __restrict__ ratios, float* __restrict__ corr) {
    int blk = blockIdx.x;
    int b = blk >> 7;                  // 128 blocks per batch
    int nt = blk & 127;
    int tid = threadIdx.x;             // m
    __shared__ float qs[NROW][128];
    {
        int r = tid >> 7, c2 = tid & 127;
        qs[r][c2] = q[((size_t)b * NSEL + nt * NROW + r) * 128 + c2];
    }
    __syncthreads();
    const float* kt = kT + (size_t)b * 128 * NSEL;
    float rel0 = 0.f, rel1 = 0.f, rel2 = 0.f, rel3 = 0.f;
#pragma unroll 4
    for (int c2 = 0; c2 < 128; ++c2) {
        float kv = kt[(size_t)c2 * NSEL + tid];
        rel0 += qs[0][c2] * kv;
        rel1 += qs[1][c2] * kv;
        rel2 += qs[2][c2] * kv;
        rel3 += qs[3][c2] * kv;
    }
    float relr[NROW] = {rel0, rel1, rel2, rel3};
    float l2x = loc2[(b * 2 + 0) * NSEL + tid];
    float l2y = loc2[(b * 2 + 1) * NSEL + tid];
    float v0 = Wv[0] * l2x + Wv[1] * l2y;
    float v1 = Wv[2] * l2x + Wv[3] * l2y;

    __shared__ float redA[NROW][8][2];
    __shared__ float redB[NROW][8][3];
    int wave = tid >> 6, lane = tid & 63;
    // phase A: per-wave top-2 for all 4 rows, one barrier
#pragma unroll
    for (int r = 0; r < NROW; ++r) {
        float b1 = relr[r], b2v = -INFINITY;
        for (int off = 32; off > 0; off >>= 1) {
            float o1 = __shfl_xor(b1, off);
            float o2 = __shfl_xor(b2v, off);
            float m1 = fmaxf(b1, o1);
            float m2 = fmaxf(fminf(b1, o1), fmaxf(b2v, o2));
            b1 = m1; b2v = m2;
        }
        if (lane == 0) { redA[r][wave][0] = b1; redA[r][wave][1] = b2v; }
    }
    __syncthreads();
    float top1[NROW], top2[NROW];
#pragma unroll
    for (int r = 0; r < NROW; ++r) {
        float t1 = redA[r][0][0], t2 = redA[r][0][1];
        for (int w2 = 1; w2 < 8; ++w2) {
            float o1 = redA[r][w2][0], o2 = redA[r][w2][1];
            float m1 = fmaxf(t1, o1);
            float m2 = fmaxf(fminf(t1, o1), fmaxf(t2, o2));
            t1 = m1; t2 = m2;
        }
        top1[r] = t1; top2[r] = t2;
    }
    // phase B: exp sums for all 4 rows, one barrier
#pragma unroll
    for (int r = 0; r < NROW; ++r) {
        float ex = expf(512.0f * (relr[r] - top1[r]));
        float sw = ex, swx = ex * v0, swy = ex * v1;
        for (int off = 32; off > 0; off >>= 1) {
            sw  += __shfl_xor(sw, off);
            swx += __shfl_xor(swx, off);
            swy += __shfl_xor(swy, off);
        }
        if (lane == 0) { redB[r][wave][0] = sw; redB[r][wave][1] = swx; redB[r][wave][2] = swy; }
    }
    __syncthreads();
    if (tid < NROW) {
        int r = tid;
        float s = 0.f, sx = 0.f, sy = 0.f;
        for (int w2 = 0; w2 < 8; ++w2) { s += redB[r][w2][0]; sx += redB[r][w2][1]; sy += redB[r][w2][2]; }
        int n = nt * NROW + r;
        float a1 = acosf(fminf(fmaxf(top1[r], -1.f), 1.f));
        float a2 = acosf(fminf(fmaxf(top2[r], -1.f), 1.f));
        ratios[b * NSEL + n] = a1 / a2;
        corr[(b * 2 + 0) * NSEL + n] = sx / s;
        corr[(b * 2 + 1) * NSEL + n] = sy / s;
    }
}

// ---------------------------------------------------------------------------
__global__ void finalize_kernel(const float* __restrict__ ratios,
                                const float* __restrict__ loc1, const float* __restrict__ corr,
                                float* __restrict__ out) {
    int b = blockIdx.x;
    int tid = threadIdx.x;  // 256
    __shared__ u64 keys[NSEL];
    for (int i = tid; i < NSEL; i += 256)
        keys[i] = ((u64)__float_as_uint(ratios[b * NSEL + i]) << 32) | (u32)i;
    __syncthreads();
    for (u32 k = 2; k <= NSEL; k <<= 1) {
        for (u32 j = k >> 1; j > 0; j >>= 1) {
            for (u32 i = tid; i < NSEL; i += 256) {
                u32 ixj = i ^ j;
                if (ixj > i) {
                    u64 a = keys[i], c2 = keys[ixj];
                    bool up = ((i & k) == 0);
                    if (up ? (a > c2) : (a < c2)) { keys[i] = c2; keys[ixj] = a; }
                }
            }
            __syncthreads();
        }
    }
    if (tid < NMATCH) {
        u32 n = (u32)(keys[tid] & 0xFFFFFFFFu);
        out[(b * 4 + 0) * NMATCH + tid] = loc1[(b * 2 + 0) * NSEL + n];
        out[(b * 4 + 1) * NMATCH + tid] = loc1[(b * 2 + 1) * NSEL + n];
        out[(b * 4 + 2) * NMATCH + tid] = corr[(b * 2 + 0) * NSEL + n];
        out[(b * 4 + 3) * NMATCH + tid] = corr[(b * 2 + 1) * NSEL + n];
    }
}

// ---------------------------------------------------------------------------
extern "C" void kernel_launch(void* const* d_in, const int* in_sizes, int n_in,
                              void* d_out, int out_size, void* d_ws, size_t ws_size,
                              hipStream_t stream) {
    const float* rep1_s0 = (const float*)d_in[0];
    const float* rel1_s0 = (const float*)d_in[1];
    const float* desc1_s0 = (const float*)d_in[2];
    const float* rep1_s1 = (const float*)d_in[3];
    const float* rel1_s1 = (const float*)d_in[4];
    const float* desc1_s1 = (const float*)d_in[5];
    const float* rep2_s0 = (const float*)d_in[6];
    const float* rel2_s0 = (const float*)d_in[7];
    const float* desc2_s0 = (const float*)d_in[8];
    const float* rep2_s1 = (const float*)d_in[9];
    const float* rel2_s1 = (const float*)d_in[10];
    const float* desc2_s1 = (const float*)d_in[11];
    const float* Wq = (const float*)d_in[12];
    const float* Wk = (const float*)d_in[13];
    const float* Wv = (const float*)d_in[14];
    float* out = (float*)d_out;

    char* w = (char*)d_ws;
    auto alloc = [&](size_t bytes) {
        char* p = w;
        w += (bytes + 255) & ~(size_t)255;
        return p;
    };
    u32* cnt       = (u32*)alloc(4 * sizeof(u32));
    u64* cand      = (u64*)alloc((size_t)4 * CAP * sizeof(u64));
    u32* sel_pix   = (u32*)alloc(4 * NSEL * sizeof(u32));
    float* sel_score = (float*)alloc(4 * NSEL * sizeof(float));
    float* q       = (float*)alloc((size_t)2 * NSEL * 128 * sizeof(float));
    float* kT      = (float*)alloc((size_t)2 * 128 * NSEL * sizeof(float));
    float* loc1    = (float*)alloc(2 * 2 * NSEL * sizeof(float));
    float* loc2    = (float*)alloc(2 * 2 * NSEL * sizeof(float));
    float* ratios  = (float*)alloc(2 * NSEL * sizeof(float));
    float* corr    = (float*)alloc(2 * 2 * NSEL * sizeof(float));

    zero_cnt_kernel<<<1, 64, 0, stream>>>(cnt);
    nms_all_kernel<<<4 * 960, 256, 0, stream>>>(
        rep1_s0, rep1_s1, rep2_s0, rep2_s1,
        rel1_s0, rel1_s1, rel2_s0, rel2_s1, cand, cnt);
    select512_kernel<<<4, 1024, 0, stream>>>(cand, cnt, sel_pix, sel_score);
    gather_tf_kernel<<<dim3(NSEL / KPB, 4), 256, 0, stream>>>(
        desc1_s0, desc1_s1, desc2_s0, desc2_s1, Wq, Wk,
        sel_pix, sel_score, q, kT, loc1, loc2);
    match_kernel<<<2 * (NSEL / NROW), 512, 0, stream>>>(q, kT, loc2, Wv, ratios, corr);
    finalize_kernel<<<2, 256, 0, stream>>>(ratios, loc1, corr, out);
}

// Round 3
// 459.366 us; speedup vs baseline: 1.4077x; 1.3355x over previous
//
#include <hip/hip_runtime.h>
#include <math.h>

typedef unsigned long long u64;
typedef unsigned int u32;

#define H0 384
#define W0 512
#define H1 192
#define W1 256
#define HW0 (H0*W0)   /* 196608 */
#define HW1 (H1*W1)   /* 49152  */
#define NSEL 512
#define NMATCH 128
#define BND_CAP 2048
#define NROW 4
#define KPB 16        /* keypoints per gather block */
#define NBLK_E 960    /* nms blocks per extraction */
#define SLOT 128      /* candidate slots per nms block (>= max local maxima in 256 px) */

// ---------------------------------------------------------------------------
// All 4 extractions x 2 scales in ONE launch, ZERO global atomics.
// Each block compacts its candidates into a private global slice + count.
// key = (float_bits(score) << 32) | (0xFFFFFFFF - pixel_index); descending
// key order == score desc, index asc (jax.lax.top_k tie rule).
__global__ void __launch_bounds__(256)
nms_all_kernel(const float* __restrict__ rep10, const float* __restrict__ rep11,
               const float* __restrict__ rep20, const float* __restrict__ rep21,
               const float* __restrict__ rel10, const float* __restrict__ rel11,
               const float* __restrict__ rel20, const float* __restrict__ rel21,
               u64* __restrict__ cand_blk, u32* __restrict__ cnt_blk) {
    int blk = blockIdx.x;
    int e = blk / NBLK_E;
    int r0 = blk - e * NBLK_E;
    int b = e & 1, img = e >> 1;
    int scale = (r0 < 768) ? 0 : 1;
    int pblk = scale ? (r0 - 768) : r0;
    int p = pblk * 256 + threadIdx.x;
    int H = scale ? H1 : H0, W = scale ? W1 : W0;
    int HW = H * W;
    const float* rep = scale ? (img ? rep21 : rep11) : (img ? rep20 : rep10);
    const float* rel = scale ? (img ? rel21 : rel11) : (img ? rel20 : rel10);
    rep += (size_t)b * HW;
    rel += (size_t)b * HW;

    __shared__ u32 bcnt;
    if (threadIdx.x == 0) bcnt = 0;
    __syncthreads();

    int r = p / W, c = p - r * W;
    float v = rep[p];
    bool ismax = true;
    for (int dr = -1; dr <= 1; ++dr) {
        int rr = r + dr;
        if (rr < 0 || rr >= H) continue;
        for (int dc = -1; dc <= 1; ++dc) {
            if (dr == 0 && dc == 0) continue;
            int cc = c + dc;
            if (cc < 0 || cc >= W) continue;
            ismax = ismax && (v >= rep[rr * W + cc]);
        }
    }
    if (ismax) {
        float m = sqrtf(v * rel[p]);
        if (m >= 0.7f) {
            u32 pos = atomicAdd(&bcnt, 1u);   // LDS atomic — block-local only
            int pix_base = scale ? HW0 : 0;
            u64 key = ((u64)__float_as_uint(m) << 32) |
                      (u64)(0xFFFFFFFFu - (u32)(pix_base + p));
            if (pos < SLOT) cand_blk[(size_t)blk * SLOT + pos] = key;
        }
    }
    __syncthreads();
    if (threadIdx.x == 0) cnt_blk[blk] = min(bcnt, (u32)SLOT);
}

// ---------------------------------------------------------------------------
// Exact top-512 per extraction from the per-block candidate slices.
// Scores in [0.7,1) -> fixed exponent, so byte (bits>>48)&0xFF is monotone.
__global__ void __launch_bounds__(1024)
select512_kernel(const u64* __restrict__ cand_blk, const u32* __restrict__ cnt_blk,
                 u32* __restrict__ sel_pix, float* __restrict__ sel_score) {
    int e = blockIdx.x;
    int tid = threadIdx.x;
    __shared__ u32 hist[256];
    __shared__ int s_b;
    __shared__ u32 n_top, n_bnd;
    __shared__ u64 topl[NSEL];
    __shared__ u64 bnd[BND_CAP];

    for (int i = tid; i < 256; i += 1024) hist[i] = 0;
    if (tid == 0) { n_top = 0; n_bnd = 0; }
    __syncthreads();
    for (int blk = tid; blk < NBLK_E; blk += 1024) {
        u32 c = cnt_blk[e * NBLK_E + blk];
        const u64* src = cand_blk + ((size_t)(e * NBLK_E + blk)) * SLOT;
        for (u32 j = 0; j < c; ++j)
            atomicAdd(&hist[(u32)(src[j] >> 48) & 0xFFu], 1u);
    }
    __syncthreads();
    if (tid == 0) {
        u32 acc = 0;
        int b = 255;
        for (; b >= 0; --b) {
            if (acc + hist[b] >= NSEL) break;
            acc += hist[b];
        }
        if (b < 0) b = 0;
        s_b = b;
    }
    __syncthreads();
    int bstar = s_b;
    for (int blk = tid; blk < NBLK_E; blk += 1024) {
        u32 c = cnt_blk[e * NBLK_E + blk];
        const u64* src = cand_blk + ((size_t)(e * NBLK_E + blk)) * SLOT;
        for (u32 j = 0; j < c; ++j) {
            u64 k = src[j];
            int byt = (int)((u32)(k >> 48) & 0xFFu);
            if (byt > bstar) {
                u32 p = atomicAdd(&n_top, 1u);
                if (p < NSEL) topl[p] = k;
            } else if (byt == bstar) {
                u32 p = atomicAdd(&n_bnd, 1u);
                if (p < BND_CAP) bnd[p] = k;
            }
        }
    }
    __syncthreads();
    u32 m = min(n_bnd, (u32)BND_CAP);
    u32 P = 2;
    while (P < m) P <<= 1;
    for (u32 i = tid; i < P; i += 1024)
        if (i >= m) bnd[i] = 0ull;
    __syncthreads();
    for (u32 k = 2; k <= P; k <<= 1) {
        for (u32 j = k >> 1; j > 0; j >>= 1) {
            for (u32 i = tid; i < P; i += 1024) {
                u32 ixj = i ^ j;
                if (ixj > i) {
                    u64 a = bnd[i], b2 = bnd[ixj];
                    bool up = ((i & k) == 0);
                    if (up ? (a < b2) : (a > b2)) { bnd[i] = b2; bnd[ixj] = a; }
                }
            }
            __syncthreads();
        }
    }
    u32 k1 = min(n_top, (u32)NSEL);
    if (tid < NSEL) {
        u64 k;
        if ((u32)tid < k1) k = topl[tid];
        else {
            u32 r = (u32)tid - k1;
            k = (r < m) ? bnd[r] : 0ull;
        }
        u32 pix;
        float sc;
        if (k == 0ull) { pix = 0u; sc = -1.0f; }
        else {
            pix = 0xFFFFFFFFu - (u32)(k & 0xFFFFFFFFu);
            sc = __uint_as_float((u32)(k >> 32));
        }
        sel_pix[e * NSEL + tid] = pix;
        sel_score[e * NSEL + tid] = sc;
    }
}

// ---------------------------------------------------------------------------
// Gather + transform, LDS-staged (unchanged from R2).
__global__ void __launch_bounds__(256)
gather_tf_kernel(const float* __restrict__ d1s0, const float* __restrict__ d1s1,
                 const float* __restrict__ d2s0, const float* __restrict__ d2s1,
                 const float* __restrict__ Wq, const float* __restrict__ Wk,
                 const u32* __restrict__ sel_pix, const float* __restrict__ sel_score,
                 float* __restrict__ q, float* __restrict__ kT,
                 float* __restrict__ loc1, float* __restrict__ loc2) {
    int e = blockIdx.y;
    int b = e & 1, img = e >> 1;
    int kp0 = blockIdx.x * KPB;
    int tid = threadIdx.x;
    __shared__ float Wt[128 * 129];   // Wt[c2*129+ch] = W[ch][c2]
    __shared__ float vb[128 * 36];    // vb[c2*36+kp]
    __shared__ u32 s_pix[KPB];
    __shared__ float s_sc[KPB];
    const float* W = img ? Wk : Wq;
    for (int i = tid; i < 16384; i += 256) {
        int row = i >> 7, col = i & 127;
        Wt[col * 129 + row] = W[i];
    }
    if (tid < KPB) {
        s_pix[tid] = sel_pix[e * NSEL + kp0 + tid];
        s_sc[tid] = sel_score[e * NSEL + kp0 + tid];
    }
    __syncthreads();
    for (int i = tid; i < KPB * 128; i += 256) {
        int kp = i >> 7, c2 = i & 127;
        u32 pix = s_pix[kp];
        float val;
        if (pix < (u32)HW0) {
            const float* ds = img ? d2s0 : d1s0;
            val = ds[((size_t)(b * 128 + c2)) * HW0 + pix];
        } else {
            const float* ds = img ? d2s1 : d1s1;
            val = ds[((size_t)(b * 128 + c2)) * HW1 + (pix - HW0)];
        }
        vb[c2 * 36 + kp] = val * s_sc[kp];
    }
    __syncthreads();
    int ch = tid & 127;
    int half = tid >> 7;               // each half: 2 groups of 4 kp
    for (int g = half * 2; g < half * 2 + 2; ++g) {
        float ax = 0.f, ay = 0.f, az = 0.f, aw = 0.f;
#pragma unroll 4
        for (int c2 = 0; c2 < 128; ++c2) {
            float w = Wt[c2 * 129 + ch];
            const float4 v4 = *(const float4*)&vb[c2 * 36 + g * 4];
            ax += w * v4.x; ay += w * v4.y; az += w * v4.z; aw += w * v4.w;
        }
        int n0 = kp0 + g * 4;
        if (img == 0) {
            q[((size_t)(b * NSEL) + n0 + 0) * 128 + ch] = ax;
            q[((size_t)(b * NSEL) + n0 + 1) * 128 + ch] = ay;
            q[((size_t)(b * NSEL) + n0 + 2) * 128 + ch] = az;
            q[((size_t)(b * NSEL) + n0 + 3) * 128 + ch] = aw;
        } else {
            float4* kr = (float4*)(kT + ((size_t)(b * 128) + ch) * NSEL + n0);
            *kr = make_float4(ax, ay, az, aw);
        }
    }
    if (tid < KPB) {
        u32 pix = s_pix[tid];
        float lr, lc;
        if (pix < (u32)HW0) { lr = (float)(pix >> 9); lc = (float)(pix & 511u); }
        else { u32 p1 = pix - HW0; lr = 2.f * (float)(p1 >> 8); lc = 2.f * (float)(p1 & 255u); }
        float* L = (img == 0) ? loc1 : loc2;
        L[(b * 2 + 0) * NSEL + kp0 + tid] = lr;
        L[(b * 2 + 1) * NSEL + kp0 + tid] = lc;
    }
}

// ---------------------------------------------------------------------------
// Fused match (unchanged from R2): rel rows, top-2, softmax expectation, ratio.
__global__ void __launch_bounds__(512)
match_kernel(const float* __restrict__ q, const float* __restrict__ kT,
             const float* __restrict__ loc2, const float* __restrict__ Wv,
             float* __restrict__ ratios, float* __restrict__ corr) {
    int blk = blockIdx.x;
    int b = blk >> 7;                  // 128 blocks per batch
    int nt = blk & 127;
    int tid = threadIdx.x;             // m
    __shared__ float qs[NROW][128];
    {
        int r = tid >> 7, c2 = tid & 127;
        qs[r][c2] = q[((size_t)b * NSEL + nt * NROW + r) * 128 + c2];
    }
    __syncthreads();
    const float* kt = kT + (size_t)b * 128 * NSEL;
    float rel0 = 0.f, rel1 = 0.f, rel2 = 0.f, rel3 = 0.f;
#pragma unroll 4
    for (int c2 = 0; c2 < 128; ++c2) {
        float kv = kt[(size_t)c2 * NSEL + tid];
        rel0 += qs[0][c2] * kv;
        rel1 += qs[1][c2] * kv;
        rel2 += qs[2][c2] * kv;
        rel3 += qs[3][c2] * kv;
    }
    float relr[NROW] = {rel0, rel1, rel2, rel3};
    float l2x = loc2[(b * 2 + 0) * NSEL + tid];
    float l2y = loc2[(b * 2 + 1) * NSEL + tid];
    float v0 = Wv[0] * l2x + Wv[1] * l2y;
    float v1 = Wv[2] * l2x + Wv[3] * l2y;

    __shared__ float redA[NROW][8][2];
    __shared__ float redB[NROW][8][3];
    int wave = tid >> 6, lane = tid & 63;
#pragma unroll
    for (int r = 0; r < NROW; ++r) {
        float b1 = relr[r], b2v = -INFINITY;
        for (int off = 32; off > 0; off >>= 1) {
            float o1 = __shfl_xor(b1, off);
            float o2 = __shfl_xor(b2v, off);
            float m1 = fmaxf(b1, o1);
            float m2 = fmaxf(fminf(b1, o1), fmaxf(b2v, o2));
            b1 = m1; b2v = m2;
        }
        if (lane == 0) { redA[r][wave][0] = b1; redA[r][wave][1] = b2v; }
    }
    __syncthreads();
    float top1[NROW], top2[NROW];
#pragma unroll
    for (int r = 0; r < NROW; ++r) {
        float t1 = redA[r][0][0], t2 = redA[r][0][1];
        for (int w2 = 1; w2 < 8; ++w2) {
            float o1 = redA[r][w2][0], o2 = redA[r][w2][1];
            float m1 = fmaxf(t1, o1);
            float m2 = fmaxf(fminf(t1, o1), fmaxf(t2, o2));
            t1 = m1; t2 = m2;
        }
        top1[r] = t1; top2[r] = t2;
    }
#pragma unroll
    for (int r = 0; r < NROW; ++r) {
        float ex = expf(512.0f * (relr[r] - top1[r]));
        float sw = ex, swx = ex * v0, swy = ex * v1;
        for (int off = 32; off > 0; off >>= 1) {
            sw  += __shfl_xor(sw, off);
            swx += __shfl_xor(swx, off);
            swy += __shfl_xor(swy, off);
        }
        if (lane == 0) { redB[r][wave][0] = sw; redB[r][wave][1] = swx; redB[r][wave][2] = swy; }
    }
    __syncthreads();
    if (tid < NROW) {
        int r = tid;
        float s = 0.f, sx = 0.f, sy = 0.f;
        for (int w2 = 0; w2 < 8; ++w2) { s += redB[r][w2][0]; sx += redB[r][w2][1]; sy += redB[r][w2][2]; }
        int n = nt * NROW + r;
        float a1 = acosf(fminf(fmaxf(top1[r], -1.f), 1.f));
        float a2 = acosf(fminf(fmaxf(top2[r], -1.f), 1.f));
        ratios[b * NSEL + n] = a1 / a2;
        corr[(b * 2 + 0) * NSEL + n] = sx / s;
        corr[(b * 2 + 1) * NSEL + n] = sy / s;
    }
}

// ---------------------------------------------------------------------------
__global__ void finalize_kernel(const float* __restrict__ ratios,
                                const float* __restrict__ loc1, const float* __restrict__ corr,
                                float* __restrict__ out) {
    int b = blockIdx.x;
    int tid = threadIdx.x;  // 256
    __shared__ u64 keys[NSEL];
    for (int i = tid; i < NSEL; i += 256)
        keys[i] = ((u64)__float_as_uint(ratios[b * NSEL + i]) << 32) | (u32)i;
    __syncthreads();
    for (u32 k = 2; k <= NSEL; k <<= 1) {
        for (u32 j = k >> 1; j > 0; j >>= 1) {
            for (u32 i = tid; i < NSEL; i += 256) {
                u32 ixj = i ^ j;
                if (ixj > i) {
                    u64 a = keys[i], c2 = keys[ixj];
                    bool up = ((i & k) == 0);
                    if (up ? (a > c2) : (a < c2)) { keys[i] = c2; keys[ixj] = a; }
                }
            }
            __syncthreads();
        }
    }
    if (tid < NMATCH) {
        u32 n = (u32)(keys[tid] & 0xFFFFFFFFu);
        out[(b * 4 + 0) * NMATCH + tid] = loc1[(b * 2 + 0) * NSEL + n];
        out[(b * 4 + 1) * NMATCH + tid] = loc1[(b * 2 + 1) * NSEL + n];
        out[(b * 4 + 2) * NMATCH + tid] = corr[(b * 2 + 0) * NSEL + n];
        out[(b * 4 + 3) * NMATCH + tid] = corr[(b * 2 + 1) * NSEL + n];
    }
}

// ---------------------------------------------------------------------------
extern "C" void kernel_launch(void* const* d_in, const int* in_sizes, int n_in,
                              void* d_out, int out_size, void* d_ws, size_t ws_size,
                              hipStream_t stream) {
    const float* rep1_s0 = (const float*)d_in[0];
    const float* rel1_s0 = (const float*)d_in[1];
    const float* desc1_s0 = (const float*)d_in[2];
    const float* rep1_s1 = (const float*)d_in[3];
    const float* rel1_s1 = (const float*)d_in[4];
    const float* desc1_s1 = (const float*)d_in[5];
    const float* rep2_s0 = (const float*)d_in[6];
    const float* rel2_s0 = (const float*)d_in[7];
    const float* desc2_s0 = (const float*)d_in[8];
    const float* rep2_s1 = (const float*)d_in[9];
    const float* rel2_s1 = (const float*)d_in[10];
    const float* desc2_s1 = (const float*)d_in[11];
    const float* Wq = (const float*)d_in[12];
    const float* Wk = (const float*)d_in[13];
    const float* Wv = (const float*)d_in[14];
    float* out = (float*)d_out;

    char* w = (char*)d_ws;
    auto alloc = [&](size_t bytes) {
        char* p = w;
        w += (bytes + 255) & ~(size_t)255;
        return p;
    };
    u64* cand_blk  = (u64*)alloc((size_t)4 * NBLK_E * SLOT * sizeof(u64));
    u32* cnt_blk   = (u32*)alloc((size_t)4 * NBLK_E * sizeof(u32));
    u32* sel_pix   = (u32*)alloc(4 * NSEL * sizeof(u32));
    float* sel_score = (float*)alloc(4 * NSEL * sizeof(float));
    float* q       = (float*)alloc((size_t)2 * NSEL * 128 * sizeof(float));
    float* kT      = (float*)alloc((size_t)2 * 128 * NSEL * sizeof(float));
    float* loc1    = (float*)alloc(2 * 2 * NSEL * sizeof(float));
    float* loc2    = (float*)alloc(2 * 2 * NSEL * sizeof(float));
    float* ratios  = (float*)alloc(2 * NSEL * sizeof(float));
    float* corr    = (float*)alloc(2 * 2 * NSEL * sizeof(float));

    nms_all_kernel<<<4 * NBLK_E, 256, 0, stream>>>(
        rep1_s0, rep1_s1, rep2_s0, rep2_s1,
        rel1_s0, rel1_s1, rel2_s0, rel2_s1, cand_blk, cnt_blk);
    select512_kernel<<<4, 1024, 0, stream>>>(cand_blk, cnt_blk, sel_pix, sel_score);
    gather_tf_kernel<<<dim3(NSEL / KPB, 4), 256, 0, stream>>>(
        desc1_s0, desc1_s1, desc2_s0, desc2_s1, Wq, Wk,
        sel_pix, sel_score, q, kT, loc1, loc2);
    match_kernel<<<2 * (NSEL / NROW), 512, 0, stream>>>(q, kT, loc2, Wv, ratios, corr);
    finalize_kernel<<<2, 256, 0, stream>>>(ratios, loc1, corr, out);
}

// Round 4
// 458.234 us; speedup vs baseline: 1.4112x; 1.0025x over previous
//
#include <hip/hip_runtime.h>
#include <math.h>

typedef unsigned long long u64;
typedef unsigned int u32;

#define H0 384
#define W0 512
#define H1 192
#define W1 256
#define HW0 (H0*W0)   /* 196608 */
#define HW1 (H1*W1)   /* 49152  */
#define NSEL 512
#define NMATCH 128
#define BND_CAP 2048
#define NROW 4
#define KPB 8          /* keypoints per gather block */
#define NSLICE_E 3840  /* wave slices per extraction (983040/4/64) */
#define SLOTW 32       /* slots per wave slice (max local maxima in 64 px) */

// ---------------------------------------------------------------------------
// All 4 extractions x 2 scales in ONE launch. Zero atomics, zero barriers:
// each wave compacts its candidates into a private 32-slot slice via ballot.
// key = (float_bits(score) << 32) | (0xFFFFFFFF - pixel_index); descending
// key order == score desc, index asc (jax.lax.top_k tie rule).
__global__ void __launch_bounds__(256)
nms_all_kernel(const float* __restrict__ rep10, const float* __restrict__ rep11,
               const float* __restrict__ rep20, const float* __restrict__ rep21,
               const float* __restrict__ rel10, const float* __restrict__ rel11,
               const float* __restrict__ rel20, const float* __restrict__ rel21,
               u64* __restrict__ cand, u32* __restrict__ cnt) {
    int blk = blockIdx.x;
    int e = blk / 960;
    int r0 = blk - e * 960;
    int b = e & 1, img = e >> 1;
    int scale = (r0 < 768) ? 0 : 1;
    int pblk = scale ? (r0 - 768) : r0;
    int p = pblk * 256 + threadIdx.x;
    int H = scale ? H1 : H0, W = scale ? W1 : W0;
    int HW = H * W;
    const float* rep = scale ? (img ? rep21 : rep11) : (img ? rep20 : rep10);
    const float* rel = scale ? (img ? rel21 : rel11) : (img ? rel20 : rel10);
    rep += (size_t)b * HW;
    rel += (size_t)b * HW;

    int r = p / W, c = p - r * W;
    float v = rep[p];
    bool ismax = true;
    for (int dr = -1; dr <= 1; ++dr) {
        int rr = r + dr;
        if (rr < 0 || rr >= H) continue;
        for (int dc = -1; dc <= 1; ++dc) {
            if (dr == 0 && dc == 0) continue;
            int cc = c + dc;
            if (cc < 0 || cc >= W) continue;
            ismax = ismax && (v >= rep[rr * W + cc]);
        }
    }
    float m = ismax ? sqrtf(v * rel[p]) : -1.0f;
    bool pass = ismax && (m >= 0.7f);
    u64 mask = __ballot(pass);
    int lane = threadIdx.x & 63;
    int wave = threadIdx.x >> 6;
    int slice = blk * 4 + wave;         // global wave-slice id
    if (pass) {
        u32 prefix = (u32)__popcll(mask & ((1ull << lane) - 1ull));
        int pix_base = scale ? HW0 : 0;
        u64 key = ((u64)__float_as_uint(m) << 32) |
                  (u64)(0xFFFFFFFFu - (u32)(pix_base + p));
        cand[(size_t)slice * SLOTW + prefix] = key;
    }
    if (lane == 0) cnt[slice] = (u32)__popcll(mask);
}

// ---------------------------------------------------------------------------
// Exact top-512 per extraction from per-wave candidate slices.
// Scores in [0.7,1) -> fixed exponent, byte (bits>>48)&0xFF monotone.
// Threshold byte found via parallel suffix-sum (no serial thread-0 scan).
__global__ void __launch_bounds__(1024)
select512_kernel(const u64* __restrict__ cand, const u32* __restrict__ cnt,
                 u32* __restrict__ sel_pix, float* __restrict__ sel_score) {
    int e = blockIdx.x;
    int tid = threadIdx.x;
    __shared__ u32 hist[256];
    __shared__ u32 T[256];
    __shared__ int s_b;
    __shared__ u32 n_top, n_bnd;
    __shared__ u64 topl[NSEL];
    __shared__ u64 bnd[BND_CAP];

    for (int i = tid; i < 256; i += 1024) hist[i] = 0;
    if (tid == 0) { n_top = 0; n_bnd = 0; s_b = 0; }
    __syncthreads();
    for (int sl = tid; sl < NSLICE_E; sl += 1024) {
        int gsl = e * NSLICE_E + sl;
        u32 c = cnt[gsl];
        const u64* src = cand + (size_t)gsl * SLOTW;
        for (u32 j = 0; j < c; ++j)
            atomicAdd(&hist[(u32)(src[j] >> 48) & 0xFFu], 1u);
    }
    __syncthreads();
    // parallel inclusive-from-top suffix sum over hist
    if (tid < 256) T[tid] = hist[tid];
    __syncthreads();
    for (int off = 1; off < 256; off <<= 1) {
        u32 add = 0;
        if (tid < 256 && tid + off < 256) add = T[tid + off];
        __syncthreads();
        if (tid < 256) T[tid] += add;
        __syncthreads();
    }
    if (tid < 256) {
        bool hit = (T[tid] >= NSEL) && (tid == 255 || T[tid + 1] < NSEL);
        if (hit) s_b = tid;
    }
    __syncthreads();
    int bstar = s_b;
    for (int sl = tid; sl < NSLICE_E; sl += 1024) {
        int gsl = e * NSLICE_E + sl;
        u32 c = cnt[gsl];
        const u64* src = cand + (size_t)gsl * SLOTW;
        for (u32 j = 0; j < c; ++j) {
            u64 k = src[j];
            int byt = (int)((u32)(k >> 48) & 0xFFu);
            if (byt > bstar) {
                u32 p = atomicAdd(&n_top, 1u);
                if (p < NSEL) topl[p] = k;
            } else if (byt == bstar) {
                u32 p = atomicAdd(&n_bnd, 1u);
                if (p < BND_CAP) bnd[p] = k;
            }
        }
    }
    __syncthreads();
    u32 m = min(n_bnd, (u32)BND_CAP);
    u32 P = 2;
    while (P < m) P <<= 1;
    for (u32 i = tid; i < P; i += 1024)
        if (i >= m) bnd[i] = 0ull;
    __syncthreads();
    for (u32 k = 2; k <= P; k <<= 1) {
        for (u32 j = k >> 1; j > 0; j >>= 1) {
            for (u32 i = tid; i < P; i += 1024) {
                u32 ixj = i ^ j;
                if (ixj > i) {
                    u64 a = bnd[i], b2 = bnd[ixj];
                    bool up = ((i & k) == 0);
                    if (up ? (a < b2) : (a > b2)) { bnd[i] = b2; bnd[ixj] = a; }
                }
            }
            __syncthreads();
        }
    }
    u32 k1 = min(n_top, (u32)NSEL);
    if (tid < NSEL) {
        u64 k;
        if ((u32)tid < k1) k = topl[tid];
        else {
            u32 r = (u32)tid - k1;
            k = (r < m) ? bnd[r] : 0ull;
        }
        u32 pix;
        float sc;
        if (k == 0ull) { pix = 0u; sc = -1.0f; }
        else {
            pix = 0xFFFFFFFFu - (u32)(k & 0xFFFFFFFFu);
            sc = __uint_as_float((u32)(k >> 32));
        }
        sel_pix[e * NSEL + tid] = pix;
        sel_score[e * NSEL + tid] = sc;
    }
}

// ---------------------------------------------------------------------------
// Gather + transform, LDS-staged. KPB=8 -> 256 blocks (double the CUs of R3),
// 4 scattered HBM gathers per thread instead of 8.
__global__ void __launch_bounds__(256)
gather_tf_kernel(const float* __restrict__ d1s0, const float* __restrict__ d1s1,
                 const float* __restrict__ d2s0, const float* __restrict__ d2s1,
                 const float* __restrict__ Wq, const float* __restrict__ Wk,
                 const u32* __restrict__ sel_pix, const float* __restrict__ sel_score,
                 float* __restrict__ q, float* __restrict__ kT,
                 float* __restrict__ loc1, float* __restrict__ loc2) {
    int e = blockIdx.y;
    int b = e & 1, img = e >> 1;
    int kp0 = blockIdx.x * KPB;
    int tid = threadIdx.x;
    __shared__ float Wt[128 * 129];   // Wt[c2*129+ch] = W[ch][c2]
    __shared__ float vb[128 * 12];    // vb[c2*12+kp], kp<8
    __shared__ u32 s_pix[KPB];
    __shared__ float s_sc[KPB];
    const float* W = img ? Wk : Wq;
    for (int i = tid; i < 16384; i += 256) {
        int row = i >> 7, col = i & 127;
        Wt[col * 129 + row] = W[i];
    }
    if (tid < KPB) {
        s_pix[tid] = sel_pix[e * NSEL + kp0 + tid];
        s_sc[tid] = sel_score[e * NSEL + kp0 + tid];
    }
    __syncthreads();
    for (int i = tid; i < KPB * 128; i += 256) {
        int kp = i >> 7, c2 = i & 127;
        u32 pix = s_pix[kp];
        float val;
        if (pix < (u32)HW0) {
            const float* ds = img ? d2s0 : d1s0;
            val = ds[((size_t)(b * 128 + c2)) * HW0 + pix];
        } else {
            const float* ds = img ? d2s1 : d1s1;
            val = ds[((size_t)(b * 128 + c2)) * HW1 + (pix - HW0)];
        }
        vb[c2 * 12 + kp] = val * s_sc[kp];
    }
    __syncthreads();
    int ch = tid & 127;
    int g = tid >> 7;                  // group of 4 keypoints
    float ax = 0.f, ay = 0.f, az = 0.f, aw = 0.f;
#pragma unroll 4
    for (int c2 = 0; c2 < 128; ++c2) {
        float w = Wt[c2 * 129 + ch];
        const float4 v4 = *(const float4*)&vb[c2 * 12 + g * 4];
        ax += w * v4.x; ay += w * v4.y; az += w * v4.z; aw += w * v4.w;
    }
    int n0 = kp0 + g * 4;
    if (img == 0) {
        q[((size_t)(b * NSEL) + n0 + 0) * 128 + ch] = ax;
        q[((size_t)(b * NSEL) + n0 + 1) * 128 + ch] = ay;
        q[((size_t)(b * NSEL) + n0 + 2) * 128 + ch] = az;
        q[((size_t)(b * NSEL) + n0 + 3) * 128 + ch] = aw;
    } else {
        float4* kr = (float4*)(kT + ((size_t)(b * 128) + ch) * NSEL + n0);
        *kr = make_float4(ax, ay, az, aw);
    }
    if (tid < KPB) {
        u32 pix = s_pix[tid];
        float lr, lc;
        if (pix < (u32)HW0) { lr = (float)(pix >> 9); lc = (float)(pix & 511u); }
        else { u32 p1 = pix - HW0; lr = 2.f * (float)(p1 >> 8); lc = 2.f * (float)(p1 & 255u); }
        float* L = (img == 0) ? loc1 : loc2;
        L[(b * 2 + 0) * NSEL + kp0 + tid] = lr;
        L[(b * 2 + 1) * NSEL + kp0 + tid] = lc;
    }
}

// ---------------------------------------------------------------------------
// Fused match: rel rows, top-2, softmax(rel*512) expectation, acos ratio.
__global__ void __launch_bounds__(512)
match_kernel(const float* __restrict__ q, const float* __restrict__ kT,
             const float* __restrict__ loc2, const float* __restrict__ Wv,
             float* __restrict__ ratios, float* __restrict__ corr) {
    int blk = blockIdx.x;
    int b = blk >> 7;
    int nt = blk & 127;
    int tid = threadIdx.x;             // m
    __shared__ float qs[NROW][128];
    {
        int r = tid >> 7, c2 = tid & 127;
        qs[r][c2] = q[((size_t)b * NSEL + nt * NROW + r) * 128 + c2];
    }
    __syncthreads();
    const float* kt = kT + (size_t)b * 128 * NSEL;
    float rel0 = 0.f, rel1 = 0.f, rel2 = 0.f, rel3 = 0.f;
#pragma unroll 4
    for (int c2 = 0; c2 < 128; ++c2) {
        float kv = kt[(size_t)c2 * NSEL + tid];
        rel0 += qs[0][c2] * kv;
        rel1 += qs[1][c2] * kv;
        rel2 += qs[2][c2] * kv;
        rel3 += qs[3][c2] * kv;
    }
    float relr[NROW] = {rel0, rel1, rel2, rel3};
    float l2x = loc2[(b * 2 + 0) * NSEL + tid];
    float l2y = loc2[(b * 2 + 1) * NSEL + tid];
    float v0 = Wv[0] * l2x + Wv[1] * l2y;
    float v1 = Wv[2] * l2x + Wv[3] * l2y;

    __shared__ float redA[NROW][8][2];
    __shared__ float redB[NROW][8][3];
    int wave = tid >> 6, lane = tid & 63;
#pragma unroll
    for (int r = 0; r < NROW; ++r) {
        float b1 = relr[r], b2v = -INFINITY;
        for (int off = 32; off > 0; off >>= 1) {
            float o1 = __shfl_xor(b1, off);
            float o2 = __shfl_xor(b2v, off);
            float m1 = fmaxf(b1, o1);
            float m2 = fmaxf(fminf(b1, o1), fmaxf(b2v, o2));
            b1 = m1; b2v = m2;
        }
        if (lane == 0) { redA[r][wave][0] = b1; redA[r][wave][1] = b2v; }
    }
    __syncthreads();
    float top1[NROW], top2[NROW];
#pragma unroll
    for (int r = 0; r < NROW; ++r) {
        float t1 = redA[r][0][0], t2 = redA[r][0][1];
        for (int w2 = 1; w2 < 8; ++w2) {
            float o1 = redA[r][w2][0], o2 = redA[r][w2][1];
            float m1 = fmaxf(t1, o1);
            float m2 = fmaxf(fminf(t1, o1), fmaxf(t2, o2));
            t1 = m1; t2 = m2;
        }
        top1[r] = t1; top2[r] = t2;
    }
#pragma unroll
    for (int r = 0; r < NROW; ++r) {
        float ex = expf(512.0f * (relr[r] - top1[r]));
        float sw = ex, swx = ex * v0, swy = ex * v1;
        for (int off = 32; off > 0; off >>= 1) {
            sw  += __shfl_xor(sw, off);
            swx += __shfl_xor(swx, off);
            swy += __shfl_xor(swy, off);
        }
        if (lane == 0) { redB[r][wave][0] = sw; redB[r][wave][1] = swx; redB[r][wave][2] = swy; }
    }
    __syncthreads();
    if (tid < NROW) {
        int r = tid;
        float s = 0.f, sx = 0.f, sy = 0.f;
        for (int w2 = 0; w2 < 8; ++w2) { s += redB[r][w2][0]; sx += redB[r][w2][1]; sy += redB[r][w2][2]; }
        int n = nt * NROW + r;
        float a1 = acosf(fminf(fmaxf(top1[r], -1.f), 1.f));
        float a2 = acosf(fminf(fmaxf(top2[r], -1.f), 1.f));
        ratios[b * NSEL + n] = a1 / a2;
        corr[(b * 2 + 0) * NSEL + n] = sx / s;
        corr[(b * 2 + 1) * NSEL + n] = sy / s;
    }
}

// ---------------------------------------------------------------------------
__global__ void finalize_kernel(const float* __restrict__ ratios,
                                const float* __restrict__ loc1, const float* __restrict__ corr,
                                float* __restrict__ out) {
    int b = blockIdx.x;
    int tid = threadIdx.x;  // 256
    __shared__ u64 keys[NSEL];
    for (int i = tid; i < NSEL; i += 256)
        keys[i] = ((u64)__float_as_uint(ratios[b * NSEL + i]) << 32) | (u32)i;
    __syncthreads();
    for (u32 k = 2; k <= NSEL; k <<= 1) {
        for (u32 j = k >> 1; j > 0; j >>= 1) {
            for (u32 i = tid; i < NSEL; i += 256) {
                u32 ixj = i ^ j;
                if (ixj > i) {
                    u64 a = keys[i], c2 = keys[ixj];
                    bool up = ((i & k) == 0);
                    if (up ? (a > c2) : (a < c2)) { keys[i] = c2; keys[ixj] = a; }
                }
            }
            __syncthreads();
        }
    }
    if (tid < NMATCH) {
        u32 n = (u32)(keys[tid] & 0xFFFFFFFFu);
        out[(b * 4 + 0) * NMATCH + tid] = loc1[(b * 2 + 0) * NSEL + n];
        out[(b * 4 + 1) * NMATCH + tid] = loc1[(b * 2 + 1) * NSEL + n];
        out[(b * 4 + 2) * NMATCH + tid] = corr[(b * 2 + 0) * NSEL + n];
        out[(b * 4 + 3) * NMATCH + tid] = corr[(b * 2 + 1) * NSEL + n];
    }
}

// ---------------------------------------------------------------------------
extern "C" void kernel_launch(void* const* d_in, const int* in_sizes, int n_in,
                              void* d_out, int out_size, void* d_ws, size_t ws_size,
                              hipStream_t stream) {
    const float* rep1_s0 = (const float*)d_in[0];
    const float* rel1_s0 = (const float*)d_in[1];
    const float* desc1_s0 = (const float*)d_in[2];
    const float* rep1_s1 = (const float*)d_in[3];
    const float* rel1_s1 = (const float*)d_in[4];
    const float* desc1_s1 = (const float*)d_in[5];
    const float* rep2_s0 = (const float*)d_in[6];
    const float* rel2_s0 = (const float*)d_in[7];
    const float* desc2_s0 = (const float*)d_in[8];
    const float* rep2_s1 = (const float*)d_in[9];
    const float* rel2_s1 = (const float*)d_in[10];
    const float* desc2_s1 = (const float*)d_in[11];
    const float* Wq = (const float*)d_in[12];
    const float* Wk = (const float*)d_in[13];
    const float* Wv = (const float*)d_in[14];
    float* out = (float*)d_out;

    char* w = (char*)d_ws;
    auto alloc = [&](size_t bytes) {
        char* p = w;
        w += (bytes + 255) & ~(size_t)255;
        return p;
    };
    u64* cand      = (u64*)alloc((size_t)4 * NSLICE_E * SLOTW * sizeof(u64));
    u32* cnt       = (u32*)alloc((size_t)4 * NSLICE_E * sizeof(u32));
    u32* sel_pix   = (u32*)alloc(4 * NSEL * sizeof(u32));
    float* sel_score = (float*)alloc(4 * NSEL * sizeof(float));
    float* q       = (float*)alloc((size_t)2 * NSEL * 128 * sizeof(float));
    float* kT      = (float*)alloc((size_t)2 * 128 * NSEL * sizeof(float));
    float* loc1    = (float*)alloc(2 * 2 * NSEL * sizeof(float));
    float* loc2    = (float*)alloc(2 * 2 * NSEL * sizeof(float));
    float* ratios  = (float*)alloc(2 * NSEL * sizeof(float));
    float* corr    = (float*)alloc(2 * 2 * NSEL * sizeof(float));

    nms_all_kernel<<<4 * 960, 256, 0, stream>>>(
        rep1_s0, rep1_s1, rep2_s0, rep2_s1,
        rel1_s0, rel1_s1, rel2_s0, rel2_s1, cand, cnt);
    select512_kernel<<<4, 1024, 0, stream>>>(cand, cnt, sel_pix, sel_score);
    gather_tf_kernel<<<dim3(NSEL / KPB, 4), 256, 0, stream>>>(
        desc1_s0, desc1_s1, desc2_s0, desc2_s1, Wq, Wk,
        sel_pix, sel_score, q, kT, loc1, loc2);
    match_kernel<<<2 * (NSEL / NROW), 512, 0, stream>>>(q, kT, loc2, Wv, ratios, corr);
    finalize_kernel<<<2, 256, 0, stream>>>(ratios, loc1, corr, out);
}